// Round 4
// baseline (51.038 us; speedup 1.0000x reference)
//
#include <hip/hip_runtime.h>
#include <math.h>

#define LN_EPS 1e-5f

// Problem constants (fixed by setup_inputs): N=10, K=5, Q=5, H=256, Qtot=50
constexpr int Nn  = 10;
constexpr int Kk  = 5;
constexpr int Hh  = 256;
constexpr int QT  = 50;
constexpr int NP1 = 11;

__device__ __forceinline__ float grp16_sum(float v) {
#pragma unroll
    for (int m = 1; m < 16; m <<= 1) v += __shfl_xor(v, m);   // 4 steps, all DPP
    return v;
}
__device__ __forceinline__ float wave64_sum(float v) {
#pragma unroll
    for (int m = 1; m < 64; m <<= 1) v += __shfl_xor(v, m);
    return v;
}

// One batch per 1024-thread block (16 waves).
// A1 (64 groups): LN stats (mu,rstd) for all 100 rows, DPP-only butterflies.
// A2 (waves 0-9): apply stats to support, M + ||M||^2 + support scores.
// C  (groups 0-49): y16 = LN(query), ||y||^2, nearest-M via norm expansion,
//                   wq, cq, counts.   B (groups 56-60): softmax of scores.
// E  (waves 0-9): rectified prototype (ballot-compressed query loop), ||p||^2.
// F  (groups 0-49): logits via norm expansion reusing y16/ny from C; pred.
__global__ __launch_bounds__(1024, 8) void proto_rectify_fused(
    const float* __restrict__ support, const float* __restrict__ query,
    const float* __restrict__ gamma,   const float* __restrict__ beta,
    float* __restrict__ out, int B)
{
    const int b    = blockIdx.x;
    const int tid  = threadIdx.x;
    const int lane = tid & 63;
    const int wave = tid >> 6;   // 0..15
    const int grp  = tid >> 4;   // 0..63
    const int sub  = tid & 15;

    __shared__ float g_s[Hh], bt_s[Hh];
    __shared__ float M_s[Nn][Hh];
    __shared__ float proto_s[Nn][Hh];
    __shared__ float nM_s[Nn], np_s[Nn];
    __shared__ float score_s[Nn * Kk];
    __shared__ float wsup_s[Nn * Kk];
    __shared__ float wq_s[QT];
    __shared__ int   cq_s[QT];
    __shared__ float sstat_s[Nn * Kk][2];  // support row: mu, rstd
    __shared__ float qstat_s[QT][2];       // query row:   mu, rstd
    __shared__ int   cnt_s[Nn];

    if (tid < Hh)          g_s[tid]       = gamma[tid];
    else if (tid < 2 * Hh) bt_s[tid - Hh] = beta[tid - Hh];
    if (tid < Nn)          cnt_s[tid]     = 0;
    __syncthreads();

    const float* supB = support + (size_t)b * (Nn * Kk * Hh);
    const float* qryB = query   + (size_t)b * (QT * Hh);

    // ---------------- A1: LN stats for 100 rows across 64 groups ----------------
    for (int r = grp; r < Nn * Kk + QT; r += 64) {
        const float* row = (r < Nn * Kk) ? supB + (size_t)r * Hh
                                         : qryB + (size_t)(r - Nn * Kk) * Hh;
        float s = 0.f, ss = 0.f;
#pragma unroll
        for (int c = 0; c < 4; ++c) {
            const float4 x = *reinterpret_cast<const float4*>(row + c * 64 + sub * 4);
            s  += x.x + x.y + x.z + x.w;
            ss += x.x * x.x + x.y * x.y + x.z * x.z + x.w * x.w;
        }
        s  = grp16_sum(s);
        ss = grp16_sum(ss);
        if (sub == 0) {
            const float mu   = s * (1.0f / (float)Hh);
            const float rstd = rsqrtf(ss * (1.0f / (float)Hh) - mu * mu + LN_EPS);
            if (r < Nn * Kk) { sstat_s[r][0] = mu; sstat_s[r][1] = rstd; }
            else             { qstat_s[r - Nn * Kk][0] = mu; qstat_s[r - Nn * Kk][1] = rstd; }
        }
    }
    __syncthreads();

    // ---------------- A2: M, ||M||^2, support scores (waves 0-9) ----------------
    if (wave < Nn) {
        const int n = wave;
        const float4 g4 = *reinterpret_cast<const float4*>(g_s  + lane * 4);
        const float4 b4 = *reinterpret_cast<const float4*>(bt_s + lane * 4);
        const float* rows = supB + (size_t)n * Kk * Hh;

        float y[Kk][4];
#pragma unroll
        for (int k = 0; k < Kk; ++k) {
            const float mu   = sstat_s[n * Kk + k][0];
            const float rstd = sstat_s[n * Kk + k][1];
            const float4 x = *reinterpret_cast<const float4*>(rows + k * Hh + lane * 4);
            y[k][0] = (x.x - mu) * rstd * g4.x + b4.x;
            y[k][1] = (x.y - mu) * rstd * g4.y + b4.y;
            y[k][2] = (x.z - mu) * rstd * g4.z + b4.z;
            y[k][3] = (x.w - mu) * rstd * g4.w + b4.w;
        }
        float Mv[4];
#pragma unroll
        for (int i = 0; i < 4; ++i)
            Mv[i] = (y[0][i] + y[1][i] + y[2][i] + y[3][i] + y[4][i]) / 5.0f;
        *reinterpret_cast<float4*>(&M_s[n][lane * 4]) =
            make_float4(Mv[0], Mv[1], Mv[2], Mv[3]);

        float pm = Mv[0] * Mv[0];
        pm = fmaf(Mv[1], Mv[1], pm); pm = fmaf(Mv[2], Mv[2], pm); pm = fmaf(Mv[3], Mv[3], pm);
        pm = wave64_sum(pm);
        if (lane == 0) nM_s[n] = pm;

#pragma unroll
        for (int k = 0; k < Kk; ++k) {
            float p = y[k][0] * Mv[0];
            p = fmaf(y[k][1], Mv[1], p); p = fmaf(y[k][2], Mv[2], p); p = fmaf(y[k][3], Mv[3], p);
            p = wave64_sum(p);
            if (lane == 0) score_s[n * Kk + k] = p;
        }
    }
    __syncthreads();

    // ---------------- C (groups 0-49) + B (groups 56-60) ----------------
    float y16[16];            // kept live through F
    float ny = 0.f;
    if (grp < QT) {
        const int q = grp;
        const float* row  = qryB + (size_t)q * Hh;
        const float  mu   = qstat_s[q][0];
        const float  rstd = qstat_s[q][1];
#pragma unroll
        for (int c = 0; c < 4; ++c) {
            const int h = c * 64 + sub * 4;
            const float4 x  = *reinterpret_cast<const float4*>(row + h);
            const float4 gg = *reinterpret_cast<const float4*>(g_s + h);
            const float4 bb = *reinterpret_cast<const float4*>(bt_s + h);
            y16[c * 4 + 0] = (x.x - mu) * rstd * gg.x + bb.x;
            y16[c * 4 + 1] = (x.y - mu) * rstd * gg.y + bb.y;
            y16[c * 4 + 2] = (x.z - mu) * rstd * gg.z + bb.z;
            y16[c * 4 + 3] = (x.w - mu) * rstd * gg.w + bb.w;
        }
#pragma unroll
        for (int j = 0; j < 16; ++j) ny = fmaf(y16[j], y16[j], ny);
        ny = grp16_sum(ny);

        float bestd = INFINITY, bestdot = 0.f;
        int bestn = 0;
#pragma unroll
        for (int n = 0; n < Nn; ++n) {
            float p = 0.f;
#pragma unroll
            for (int c = 0; c < 4; ++c) {
                const float4 mv = *reinterpret_cast<const float4*>(&M_s[n][c * 64 + sub * 4]);
                p = fmaf(y16[c * 4 + 0], mv.x, p);
                p = fmaf(y16[c * 4 + 1], mv.y, p);
                p = fmaf(y16[c * 4 + 2], mv.z, p);
                p = fmaf(y16[c * 4 + 3], mv.w, p);
            }
            p = grp16_sum(p);
            const float d = ny + nM_s[n] - 2.0f * p;
            if (d < bestd) { bestd = d; bestn = n; bestdot = p; }  // first-min tie-break
        }
        if (sub == 0) {
            const float sc  = bestdot;             // <q, M_bestn>
            const float mx  = fmaxf(sc, 0.f);
            const float e   = expf(sc - mx);
            const float den = e + (float)(Nn - 1) * expf(-mx);
            wq_s[q] = e / den;
            cq_s[q] = bestn;
            atomicAdd(&cnt_s[bestn], 1);
        }
    } else if (grp >= 56 && grp < 56 + Kk && sub == 0) {
        const int k = grp - 56;
        float mx = -INFINITY;
#pragma unroll
        for (int n = 0; n < Nn; ++n) mx = fmaxf(mx, score_s[n * Kk + k]);
        float e[Nn]; float den = 0.f;
#pragma unroll
        for (int n = 0; n < Nn; ++n) { e[n] = expf(score_s[n * Kk + k] - mx); den += e[n]; }
#pragma unroll
        for (int n = 0; n < Nn; ++n) wsup_s[n * Kk + k] = e[n] / den;
    }
    __syncthreads();

    // ---------------- E (waves 0-9): rectified prototype ----------------
    if (wave < Nn) {
        const int n = wave;
        const float4 g4 = *reinterpret_cast<const float4*>(g_s  + lane * 4);
        const float4 b4 = *reinterpret_cast<const float4*>(bt_s + lane * 4);
        const float* rows = supB + (size_t)n * Kk * Hh;

        float acc[4] = {0.f, 0.f, 0.f, 0.f};
#pragma unroll
        for (int k = 0; k < Kk; ++k) {
            const float w    = wsup_s[n * Kk + k];
            const float mu   = sstat_s[n * Kk + k][0];
            const float rstd = sstat_s[n * Kk + k][1];
            const float4 x = *reinterpret_cast<const float4*>(rows + k * Hh + lane * 4);
            acc[0] = fmaf(w, (x.x - mu) * rstd * g4.x + b4.x, acc[0]);
            acc[1] = fmaf(w, (x.y - mu) * rstd * g4.y + b4.y, acc[1]);
            acc[2] = fmaf(w, (x.z - mu) * rstd * g4.z + b4.z, acc[2]);
            acc[3] = fmaf(w, (x.w - mu) * rstd * g4.w + b4.w, acc[3]);
        }
        // ballot-compressed query rectification loop (~5 hits avg)
        int myc = -1; float myw = 0.f, mymu = 0.f, myr = 0.f;
        if (lane < QT) {
            myc  = cq_s[lane]; myw = wq_s[lane];
            mymu = qstat_s[lane][0]; myr = qstat_s[lane][1];
        }
        unsigned long long mask = __ballot(lane < QT && myc == n);
        while (mask) {
            const int q = __ffsll(mask) - 1;
            mask &= mask - 1;
            const float w    = __shfl(myw,  q);
            const float mu   = __shfl(mymu, q);
            const float rstd = __shfl(myr,  q);
            const float4 x = *reinterpret_cast<const float4*>(qryB + (size_t)q * Hh + lane * 4);
            acc[0] = fmaf(w, (x.x - mu) * rstd * g4.x + b4.x, acc[0]);
            acc[1] = fmaf(w, (x.y - mu) * rstd * g4.y + b4.y, acc[1]);
            acc[2] = fmaf(w, (x.z - mu) * rstd * g4.z + b4.z, acc[2]);
            acc[3] = fmaf(w, (x.w - mu) * rstd * g4.w + b4.w, acc[3]);
        }
        const float inv = 1.0f / (float)(Kk + cnt_s[n]);
        float pv[4];
#pragma unroll
        for (int i = 0; i < 4; ++i) pv[i] = acc[i] * inv;
        *reinterpret_cast<float4*>(&proto_s[n][lane * 4]) =
            make_float4(pv[0], pv[1], pv[2], pv[3]);
        float pp = pv[0] * pv[0];
        pp = fmaf(pv[1], pv[1], pp); pp = fmaf(pv[2], pv[2], pp); pp = fmaf(pv[3], pv[3], pp);
        pp = wave64_sum(pp);
        if (lane == 0) np_s[n] = pp;
    }
    __syncthreads();

    // ---------------- F (groups 0-49): logits + pred (reuse y16, ny) ----------------
    if (grp < QT) {
        const int q = grp;
        float mine = 0.f, maxd = -INFINITY, bestd = INFINITY;
        int bestn = 0;
#pragma unroll
        for (int n = 0; n < Nn; ++n) {
            float p = 0.f;
#pragma unroll
            for (int c = 0; c < 4; ++c) {
                const float4 pv = *reinterpret_cast<const float4*>(&proto_s[n][c * 64 + sub * 4]);
                p = fmaf(y16[c * 4 + 0], pv.x, p);
                p = fmaf(y16[c * 4 + 1], pv.y, p);
                p = fmaf(y16[c * 4 + 2], pv.z, p);
                p = fmaf(y16[c * 4 + 3], pv.w, p);
            }
            p = grp16_sum(p);
            const float d = ny + np_s[n] - 2.0f * p;
            if (sub == n) mine = d;
            maxd = fmaxf(maxd, d);
            if (d < bestd) { bestd = d; bestn = n; }
        }
        float* o = out + ((size_t)b * QT + q) * NP1;
        if (sub < Nn)       o[sub] = -mine;
        else if (sub == Nn) o[Nn]  = -maxd - 1.0f;             // min(logits) - 1
        else if (sub == Nn + 1)
            out[(size_t)B * QT * NP1 + (size_t)b * QT + q] = (float)bestn;
    }
}

extern "C" void kernel_launch(void* const* d_in, const int* in_sizes, int n_in,
                              void* d_out, int out_size, void* d_ws, size_t ws_size,
                              hipStream_t stream) {
    const float* support = (const float*)d_in[0];
    const float* query   = (const float*)d_in[1];
    const float* gamma   = (const float*)d_in[2];
    const float* beta    = (const float*)d_in[3];
    float* out = (float*)d_out;

    const int B = in_sizes[0] / (Nn * Kk * Hh);   // 512
    proto_rectify_fused<<<B, 1024, 0, stream>>>(support, query, gamma, beta, out, B);
}

// Round 5
// 39.382 us; speedup vs baseline: 1.2960x; 1.2960x over previous
//
#include <hip/hip_runtime.h>
#include <math.h>

#define LN_EPS 1e-5f

// Problem constants (fixed by setup_inputs): N=10, K=5, Q=5, H=256, Qtot=50
constexpr int Nn  = 10;
constexpr int Kk  = 5;
constexpr int Hh  = 256;
constexpr int QT  = 50;
constexpr int NP1 = 11;

__device__ __forceinline__ float grp16_sum(float v) {
#pragma unroll
    for (int m = 1; m < 16; m <<= 1) v += __shfl_xor(v, m);   // 4 steps, DPP-only
    return v;
}
__device__ __forceinline__ float wave64_sum(float v) {
#pragma unroll
    for (int m = 1; m < 64; m <<= 1) v += __shfl_xor(v, m);
    return v;
}

// One batch per 1024-thread block (16 waves). 4 barriers total.
// A1 (64 groups): gamma/beta -> LDS; LN stats (mu,rstd) for all 100 rows.
// A2 (waves 0-9): apply stats, M, ||M||^2, support scores.
// C  (groups 0-49): y16=LN(query), ny->LDS, nearest-M via d=ny+nM-2*dot,
//                   wq/cq/counts.   B (groups 56-60): softmax of scores.
// E  (waves 0-9): rectified prototype (ballot-compressed query loop), ||p||^2.
// F  (groups 0-49): y16 recomputed (global reload, L2-hot), logits via
//                   d=ny+np-2*dot, pred.
// NOTE: nothing lives in registers across a barrier (round-4 spill lesson:
// y16 across E -> 66MB scratch traffic). ny goes through LDS instead.
__global__ __launch_bounds__(1024, 8) void proto_rectify_fused(
    const float* __restrict__ support, const float* __restrict__ query,
    const float* __restrict__ gamma,   const float* __restrict__ beta,
    float* __restrict__ out, int B)
{
    const int b    = blockIdx.x;
    const int tid  = threadIdx.x;
    const int lane = tid & 63;
    const int wave = tid >> 6;   // 0..15
    const int grp  = tid >> 4;   // 0..63
    const int sub  = tid & 15;

    __shared__ float g_s[Hh], bt_s[Hh];
    __shared__ float M_s[Nn][Hh];
    __shared__ float proto_s[Nn][Hh];
    __shared__ float nM_s[Nn], np_s[Nn];
    __shared__ float ny_s[QT];
    __shared__ float score_s[Nn * Kk];
    __shared__ float wsup_s[Nn * Kk];
    __shared__ float wq_s[QT];
    __shared__ int   cq_s[QT];
    __shared__ float sstat_s[Nn * Kk][2];  // support row: mu, rstd
    __shared__ float qstat_s[QT][2];       // query row:   mu, rstd
    __shared__ int   cnt_s[Nn];

    const float* supB = support + (size_t)b * (Nn * Kk * Hh);
    const float* qryB = query   + (size_t)b * (QT * Hh);

    // ---------------- A1: params + LN stats for 100 rows (no prior barrier) ----
    if (tid < Hh)          g_s[tid]       = gamma[tid];
    else if (tid < 2 * Hh) bt_s[tid - Hh] = beta[tid - Hh];
    if (tid < Nn)          cnt_s[tid]     = 0;

    for (int r = grp; r < Nn * Kk + QT; r += 64) {
        const float* row = (r < Nn * Kk) ? supB + (size_t)r * Hh
                                         : qryB + (size_t)(r - Nn * Kk) * Hh;
        float s = 0.f, ss = 0.f;
#pragma unroll
        for (int c = 0; c < 4; ++c) {
            const float4 x = *reinterpret_cast<const float4*>(row + c * 64 + sub * 4);
            s  += x.x + x.y + x.z + x.w;
            ss += x.x * x.x + x.y * x.y + x.z * x.z + x.w * x.w;
        }
        s  = grp16_sum(s);
        ss = grp16_sum(ss);
        if (sub == 0) {
            const float mu   = s * (1.0f / (float)Hh);
            const float rstd = rsqrtf(ss * (1.0f / (float)Hh) - mu * mu + LN_EPS);
            if (r < Nn * Kk) { sstat_s[r][0] = mu; sstat_s[r][1] = rstd; }
            else             { qstat_s[r - Nn * Kk][0] = mu; qstat_s[r - Nn * Kk][1] = rstd; }
        }
    }
    __syncthreads();

    // ---------------- A2: M, ||M||^2, support scores (waves 0-9) ----------------
    if (wave < Nn) {
        const int n = wave;
        const float4 g4 = *reinterpret_cast<const float4*>(g_s  + lane * 4);
        const float4 b4 = *reinterpret_cast<const float4*>(bt_s + lane * 4);
        const float* rows = supB + (size_t)n * Kk * Hh;

        float y[Kk][4];
#pragma unroll
        for (int k = 0; k < Kk; ++k) {
            const float mu   = sstat_s[n * Kk + k][0];
            const float rstd = sstat_s[n * Kk + k][1];
            const float4 x = *reinterpret_cast<const float4*>(rows + k * Hh + lane * 4);
            y[k][0] = (x.x - mu) * rstd * g4.x + b4.x;
            y[k][1] = (x.y - mu) * rstd * g4.y + b4.y;
            y[k][2] = (x.z - mu) * rstd * g4.z + b4.z;
            y[k][3] = (x.w - mu) * rstd * g4.w + b4.w;
        }
        float Mv[4];
#pragma unroll
        for (int i = 0; i < 4; ++i)
            Mv[i] = (y[0][i] + y[1][i] + y[2][i] + y[3][i] + y[4][i]) / 5.0f;
        *reinterpret_cast<float4*>(&M_s[n][lane * 4]) =
            make_float4(Mv[0], Mv[1], Mv[2], Mv[3]);

        float pm = Mv[0] * Mv[0];
        pm = fmaf(Mv[1], Mv[1], pm); pm = fmaf(Mv[2], Mv[2], pm); pm = fmaf(Mv[3], Mv[3], pm);
        pm = wave64_sum(pm);
        if (lane == 0) nM_s[n] = pm;

#pragma unroll
        for (int k = 0; k < Kk; ++k) {
            float p = y[k][0] * Mv[0];
            p = fmaf(y[k][1], Mv[1], p); p = fmaf(y[k][2], Mv[2], p); p = fmaf(y[k][3], Mv[3], p);
            p = wave64_sum(p);
            if (lane == 0) score_s[n * Kk + k] = p;
        }
    }
    __syncthreads();

    // ---------------- C (groups 0-49) + B (groups 56-60) ----------------
    if (grp < QT) {
        const int q = grp;
        const float* row  = qryB + (size_t)q * Hh;
        const float  mu   = qstat_s[q][0];
        const float  rstd = qstat_s[q][1];
        float y16[16];
#pragma unroll
        for (int c = 0; c < 4; ++c) {
            const int h = c * 64 + sub * 4;
            const float4 x  = *reinterpret_cast<const float4*>(row + h);
            const float4 gg = *reinterpret_cast<const float4*>(g_s + h);
            const float4 bb = *reinterpret_cast<const float4*>(bt_s + h);
            y16[c * 4 + 0] = (x.x - mu) * rstd * gg.x + bb.x;
            y16[c * 4 + 1] = (x.y - mu) * rstd * gg.y + bb.y;
            y16[c * 4 + 2] = (x.z - mu) * rstd * gg.z + bb.z;
            y16[c * 4 + 3] = (x.w - mu) * rstd * gg.w + bb.w;
        }
        float ny = 0.f;
#pragma unroll
        for (int j = 0; j < 16; ++j) ny = fmaf(y16[j], y16[j], ny);
        ny = grp16_sum(ny);
        if (sub == 0) ny_s[q] = ny;

        float bestd = INFINITY, bestdot = 0.f;
        int bestn = 0;
#pragma unroll
        for (int n = 0; n < Nn; ++n) {
            float p = 0.f;
#pragma unroll
            for (int c = 0; c < 4; ++c) {
                const float4 mv = *reinterpret_cast<const float4*>(&M_s[n][c * 64 + sub * 4]);
                p = fmaf(y16[c * 4 + 0], mv.x, p);
                p = fmaf(y16[c * 4 + 1], mv.y, p);
                p = fmaf(y16[c * 4 + 2], mv.z, p);
                p = fmaf(y16[c * 4 + 3], mv.w, p);
            }
            p = grp16_sum(p);
            const float d = ny + nM_s[n] - 2.0f * p;
            if (d < bestd) { bestd = d; bestn = n; bestdot = p; }  // first-min tie-break
        }
        if (sub == 0) {
            const float sc  = bestdot;             // <q, M_bestn>
            const float mx  = fmaxf(sc, 0.f);
            const float e   = expf(sc - mx);
            const float den = e + (float)(Nn - 1) * expf(-mx);
            wq_s[q] = e / den;
            cq_s[q] = bestn;
            atomicAdd(&cnt_s[bestn], 1);
        }
    } else if (grp >= 56 && grp < 56 + Kk && sub == 0) {
        const int k = grp - 56;
        float mx = -INFINITY;
#pragma unroll
        for (int n = 0; n < Nn; ++n) mx = fmaxf(mx, score_s[n * Kk + k]);
        float e[Nn]; float den = 0.f;
#pragma unroll
        for (int n = 0; n < Nn; ++n) { e[n] = expf(score_s[n * Kk + k] - mx); den += e[n]; }
#pragma unroll
        for (int n = 0; n < Nn; ++n) wsup_s[n * Kk + k] = e[n] / den;
    }
    __syncthreads();

    // ---------------- E (waves 0-9): rectified prototype ----------------
    if (wave < Nn) {
        const int n = wave;
        const float4 g4 = *reinterpret_cast<const float4*>(g_s  + lane * 4);
        const float4 b4 = *reinterpret_cast<const float4*>(bt_s + lane * 4);
        const float* rows = supB + (size_t)n * Kk * Hh;

        float acc[4] = {0.f, 0.f, 0.f, 0.f};
#pragma unroll
        for (int k = 0; k < Kk; ++k) {
            const float w    = wsup_s[n * Kk + k];
            const float mu   = sstat_s[n * Kk + k][0];
            const float rstd = sstat_s[n * Kk + k][1];
            const float4 x = *reinterpret_cast<const float4*>(rows + k * Hh + lane * 4);
            acc[0] = fmaf(w, (x.x - mu) * rstd * g4.x + b4.x, acc[0]);
            acc[1] = fmaf(w, (x.y - mu) * rstd * g4.y + b4.y, acc[1]);
            acc[2] = fmaf(w, (x.z - mu) * rstd * g4.z + b4.z, acc[2]);
            acc[3] = fmaf(w, (x.w - mu) * rstd * g4.w + b4.w, acc[3]);
        }
        // ballot-compressed query rectification loop (~Q hits avg)
        int myc = -1; float myw = 0.f, mymu = 0.f, myr = 0.f;
        if (lane < QT) {
            myc  = cq_s[lane]; myw = wq_s[lane];
            mymu = qstat_s[lane][0]; myr = qstat_s[lane][1];
        }
        unsigned long long mask = __ballot(lane < QT && myc == n);
        while (mask) {
            const int q = __ffsll(mask) - 1;
            mask &= mask - 1;
            const float w    = __shfl(myw,  q);
            const float mu   = __shfl(mymu, q);
            const float rstd = __shfl(myr,  q);
            const float4 x = *reinterpret_cast<const float4*>(qryB + (size_t)q * Hh + lane * 4);
            acc[0] = fmaf(w, (x.x - mu) * rstd * g4.x + b4.x, acc[0]);
            acc[1] = fmaf(w, (x.y - mu) * rstd * g4.y + b4.y, acc[1]);
            acc[2] = fmaf(w, (x.z - mu) * rstd * g4.z + b4.z, acc[2]);
            acc[3] = fmaf(w, (x.w - mu) * rstd * g4.w + b4.w, acc[3]);
        }
        const float inv = 1.0f / (float)(Kk + cnt_s[n]);
        float pv[4];
#pragma unroll
        for (int i = 0; i < 4; ++i) pv[i] = acc[i] * inv;
        *reinterpret_cast<float4*>(&proto_s[n][lane * 4]) =
            make_float4(pv[0], pv[1], pv[2], pv[3]);
        float pp = pv[0] * pv[0];
        pp = fmaf(pv[1], pv[1], pp); pp = fmaf(pv[2], pv[2], pp); pp = fmaf(pv[3], pv[3], pp);
        pp = wave64_sum(pp);
        if (lane == 0) np_s[n] = pp;
    }
    __syncthreads();

    // ---------------- F (groups 0-49): logits + pred ----------------
    if (grp < QT) {
        const int q = grp;
        const float* row  = qryB + (size_t)q * Hh;
        const float  mu   = qstat_s[q][0];
        const float  rstd = qstat_s[q][1];
        float y16[16];
#pragma unroll
        for (int c = 0; c < 4; ++c) {
            const int h = c * 64 + sub * 4;
            const float4 x  = *reinterpret_cast<const float4*>(row + h);
            const float4 gg = *reinterpret_cast<const float4*>(g_s + h);
            const float4 bb = *reinterpret_cast<const float4*>(bt_s + h);
            y16[c * 4 + 0] = (x.x - mu) * rstd * gg.x + bb.x;
            y16[c * 4 + 1] = (x.y - mu) * rstd * gg.y + bb.y;
            y16[c * 4 + 2] = (x.z - mu) * rstd * gg.z + bb.z;
            y16[c * 4 + 3] = (x.w - mu) * rstd * gg.w + bb.w;
        }
        const float ny = ny_s[q];

        float mine = 0.f, maxd = -INFINITY, bestd = INFINITY;
        int bestn = 0;
#pragma unroll
        for (int n = 0; n < Nn; ++n) {
            float p = 0.f;
#pragma unroll
            for (int c = 0; c < 4; ++c) {
                const float4 pv = *reinterpret_cast<const float4*>(&proto_s[n][c * 64 + sub * 4]);
                p = fmaf(y16[c * 4 + 0], pv.x, p);
                p = fmaf(y16[c * 4 + 1], pv.y, p);
                p = fmaf(y16[c * 4 + 2], pv.z, p);
                p = fmaf(y16[c * 4 + 3], pv.w, p);
            }
            p = grp16_sum(p);
            const float d = ny + np_s[n] - 2.0f * p;
            if (sub == n) mine = d;
            maxd = fmaxf(maxd, d);
            if (d < bestd) { bestd = d; bestn = n; }
        }
        float* o = out + ((size_t)b * QT + q) * NP1;
        if (sub < Nn)       o[sub] = -mine;
        else if (sub == Nn) o[Nn]  = -maxd - 1.0f;             // min(logits) - 1
        else if (sub == Nn + 1)
            out[(size_t)B * QT * NP1 + (size_t)b * QT + q] = (float)bestn;
    }
}

extern "C" void kernel_launch(void* const* d_in, const int* in_sizes, int n_in,
                              void* d_out, int out_size, void* d_ws, size_t ws_size,
                              hipStream_t stream) {
    const float* support = (const float*)d_in[0];
    const float* query   = (const float*)d_in[1];
    const float* gamma   = (const float*)d_in[2];
    const float* beta    = (const float*)d_in[3];
    float* out = (float*)d_out;

    const int B = in_sizes[0] / (Nn * Kk * Hh);   // 512
    proto_rectify_fused<<<B, 1024, 0, stream>>>(support, query, gamma, beta, out, B);
}

// Round 6
// 34.280 us; speedup vs baseline: 1.4889x; 1.1488x over previous
//
#include <hip/hip_runtime.h>
#include <math.h>

#define LN_EPS 1e-5f

// Problem constants (fixed by setup_inputs): N=10, K=5, Q=5, H=256, Qtot=50
constexpr int Nn  = 10;
constexpr int Kk  = 5;
constexpr int Hh  = 256;
constexpr int QT  = 50;
constexpr int NP1 = 11;

__device__ __forceinline__ float grp16_sum(float v) {
#pragma unroll
    for (int m = 1; m < 16; m <<= 1) v += __shfl_xor(v, m);   // 4 steps, DPP-only
    return v;
}
__device__ __forceinline__ float wave64_sum(float v) {
#pragma unroll
    for (int m = 1; m < 64; m <<= 1) v += __shfl_xor(v, m);
    return v;
}

// One batch per 1024-thread block (16 waves). 3 barriers total.
// A  (waves 0-9):  LN support inline (one global read; stats -> LDS for E),
//                  M, ||M||^2, support scores.  gamma/beta read direct from
//                  global (L1), LDS copies filled concurrently for C/E/F.
// A' (waves 10-15): query LN stats (mu,rstd) -> LDS.
// C  (groups 0-49): y16=LN(query), ny->LDS, nearest-M via d=ny+nM-2*dot
//                  (best-dot falls out free), wq/cq/counts.
// B  (groups 56-60): per-k softmax over N of support scores.
// E  (waves 0-9):  rectified prototype (ballot-compressed query loop), ||p||^2.
// F  (groups 0-49): y16 recomputed (L2-hot reload), logits via d=ny+np-2*dot.
// NOTE: nothing register-live across barriers (round-4 spill lesson:
// y16 across E -> 66MB scratch traffic). Scalars cross via LDS.
__global__ __launch_bounds__(1024, 8) void proto_rectify_fused(
    const float* __restrict__ support, const float* __restrict__ query,
    const float* __restrict__ gamma,   const float* __restrict__ beta,
    float* __restrict__ out, int B)
{
    const int b    = blockIdx.x;
    const int tid  = threadIdx.x;
    const int lane = tid & 63;
    const int wave = tid >> 6;   // 0..15
    const int grp  = tid >> 4;   // 0..63
    const int sub  = tid & 15;

    __shared__ float g_s[Hh], bt_s[Hh];
    __shared__ float M_s[Nn][Hh];
    __shared__ float proto_s[Nn][Hh];
    __shared__ float nM_s[Nn], np_s[Nn];
    __shared__ float ny_s[QT];
    __shared__ float score_s[Nn * Kk];
    __shared__ float wsup_s[Nn * Kk];
    __shared__ float wq_s[QT];
    __shared__ int   cq_s[QT];
    __shared__ float sstat_s[Nn * Kk][2];  // support row: mu, rstd
    __shared__ float qstat_s[QT][2];       // query row:   mu, rstd
    __shared__ int   cnt_s[Nn];

    const float* supB = support + (size_t)b * (Nn * Kk * Hh);
    const float* qryB = query   + (size_t)b * (QT * Hh);

    // LDS preload runs concurrently with phase A (consumed only after sync 1)
    if (tid < Hh)          g_s[tid]       = gamma[tid];
    else if (tid < 2 * Hh) bt_s[tid - Hh] = beta[tid - Hh];
    if (tid < Nn)          cnt_s[tid]     = 0;

    // ---------------- Phase A / A' ----------------
    if (wave < Nn) {
        const int n = wave;
        const float4 g4 = *reinterpret_cast<const float4*>(gamma + lane * 4); // L1
        const float4 b4 = *reinterpret_cast<const float4*>(beta  + lane * 4);
        const float* rows = supB + (size_t)n * Kk * Hh;

        float y[Kk][4];
#pragma unroll
        for (int k = 0; k < Kk; ++k) {
            const float4 x = *reinterpret_cast<const float4*>(rows + k * Hh + lane * 4);
            float s  = x.x + x.y + x.z + x.w;
            float ss = x.x * x.x + x.y * x.y + x.z * x.z + x.w * x.w;
#pragma unroll
            for (int m = 1; m < 64; m <<= 1) { s += __shfl_xor(s, m); ss += __shfl_xor(ss, m); }
            const float mu   = s * (1.0f / (float)Hh);
            const float rstd = rsqrtf(ss * (1.0f / (float)Hh) - mu * mu + LN_EPS);
            if (lane == 0) { sstat_s[n * Kk + k][0] = mu; sstat_s[n * Kk + k][1] = rstd; }
            y[k][0] = (x.x - mu) * rstd * g4.x + b4.x;
            y[k][1] = (x.y - mu) * rstd * g4.y + b4.y;
            y[k][2] = (x.z - mu) * rstd * g4.z + b4.z;
            y[k][3] = (x.w - mu) * rstd * g4.w + b4.w;
        }
        float Mv[4];
#pragma unroll
        for (int i = 0; i < 4; ++i)
            Mv[i] = (y[0][i] + y[1][i] + y[2][i] + y[3][i] + y[4][i]) / 5.0f;
        *reinterpret_cast<float4*>(&M_s[n][lane * 4]) =
            make_float4(Mv[0], Mv[1], Mv[2], Mv[3]);

        float pm = Mv[0] * Mv[0];
        pm = fmaf(Mv[1], Mv[1], pm); pm = fmaf(Mv[2], Mv[2], pm); pm = fmaf(Mv[3], Mv[3], pm);
        pm = wave64_sum(pm);
        if (lane == 0) nM_s[n] = pm;

#pragma unroll
        for (int k = 0; k < Kk; ++k) {
            float p = y[k][0] * Mv[0];
            p = fmaf(y[k][1], Mv[1], p); p = fmaf(y[k][2], Mv[2], p); p = fmaf(y[k][3], Mv[3], p);
            p = wave64_sum(p);
            if (lane == 0) score_s[n * Kk + k] = p;
        }
    } else {
        // waves 10..15 -> groups 40..63 (24 groups): query LN stats
        for (int q = grp - 40; q < QT; q += 24) {
            const float* row = qryB + (size_t)q * Hh;
            float s = 0.f, ss = 0.f;
#pragma unroll
            for (int c = 0; c < 4; ++c) {
                const float4 x = *reinterpret_cast<const float4*>(row + c * 64 + sub * 4);
                s  += x.x + x.y + x.z + x.w;
                ss += x.x * x.x + x.y * x.y + x.z * x.z + x.w * x.w;
            }
            s  = grp16_sum(s);
            ss = grp16_sum(ss);
            if (sub == 0) {
                const float mu = s * (1.0f / (float)Hh);
                qstat_s[q][0] = mu;
                qstat_s[q][1] = rsqrtf(ss * (1.0f / (float)Hh) - mu * mu + LN_EPS);
            }
        }
    }
    __syncthreads();

    // ---------------- C (groups 0-49) + B (groups 56-60) ----------------
    if (grp < QT) {
        const int q = grp;
        const float* row  = qryB + (size_t)q * Hh;
        const float  mu   = qstat_s[q][0];
        const float  rstd = qstat_s[q][1];
        float y16[16];
#pragma unroll
        for (int c = 0; c < 4; ++c) {
            const int h = c * 64 + sub * 4;
            const float4 x  = *reinterpret_cast<const float4*>(row + h);
            const float4 gg = *reinterpret_cast<const float4*>(g_s + h);
            const float4 bb = *reinterpret_cast<const float4*>(bt_s + h);
            y16[c * 4 + 0] = (x.x - mu) * rstd * gg.x + bb.x;
            y16[c * 4 + 1] = (x.y - mu) * rstd * gg.y + bb.y;
            y16[c * 4 + 2] = (x.z - mu) * rstd * gg.z + bb.z;
            y16[c * 4 + 3] = (x.w - mu) * rstd * gg.w + bb.w;
        }
        float ny = 0.f;
#pragma unroll
        for (int j = 0; j < 16; ++j) ny = fmaf(y16[j], y16[j], ny);
        ny = grp16_sum(ny);
        if (sub == 0) ny_s[q] = ny;

        float bestd = INFINITY, bestdot = 0.f;
        int bestn = 0;
#pragma unroll
        for (int n = 0; n < Nn; ++n) {
            float p = 0.f;
#pragma unroll
            for (int c = 0; c < 4; ++c) {
                const float4 mv = *reinterpret_cast<const float4*>(&M_s[n][c * 64 + sub * 4]);
                p = fmaf(y16[c * 4 + 0], mv.x, p);
                p = fmaf(y16[c * 4 + 1], mv.y, p);
                p = fmaf(y16[c * 4 + 2], mv.z, p);
                p = fmaf(y16[c * 4 + 3], mv.w, p);
            }
            p = grp16_sum(p);
            const float d = ny + nM_s[n] - 2.0f * p;
            if (d < bestd) { bestd = d; bestn = n; bestdot = p; }  // first-min tie-break
        }
        if (sub == 0) {
            const float sc  = bestdot;             // <q, M_bestn>
            const float mx  = fmaxf(sc, 0.f);
            const float e   = expf(sc - mx);
            const float den = e + (float)(Nn - 1) * expf(-mx);
            wq_s[q] = e / den;
            cq_s[q] = bestn;
            atomicAdd(&cnt_s[bestn], 1);
        }
    } else if (grp >= 56 && grp < 56 + Kk && sub == 0) {
        const int k = grp - 56;
        float mx = -INFINITY;
#pragma unroll
        for (int n = 0; n < Nn; ++n) mx = fmaxf(mx, score_s[n * Kk + k]);
        float e[Nn]; float den = 0.f;
#pragma unroll
        for (int n = 0; n < Nn; ++n) { e[n] = expf(score_s[n * Kk + k] - mx); den += e[n]; }
#pragma unroll
        for (int n = 0; n < Nn; ++n) wsup_s[n * Kk + k] = e[n] / den;
    }
    __syncthreads();

    // ---------------- E (waves 0-9): rectified prototype ----------------
    if (wave < Nn) {
        const int n = wave;
        const float4 g4 = *reinterpret_cast<const float4*>(g_s  + lane * 4);
        const float4 b4 = *reinterpret_cast<const float4*>(bt_s + lane * 4);
        const float* rows = supB + (size_t)n * Kk * Hh;

        float acc[4] = {0.f, 0.f, 0.f, 0.f};
#pragma unroll
        for (int k = 0; k < Kk; ++k) {
            const float w    = wsup_s[n * Kk + k];
            const float mu   = sstat_s[n * Kk + k][0];
            const float rstd = sstat_s[n * Kk + k][1];
            const float4 x = *reinterpret_cast<const float4*>(rows + k * Hh + lane * 4);
            acc[0] = fmaf(w, (x.x - mu) * rstd * g4.x + b4.x, acc[0]);
            acc[1] = fmaf(w, (x.y - mu) * rstd * g4.y + b4.y, acc[1]);
            acc[2] = fmaf(w, (x.z - mu) * rstd * g4.z + b4.z, acc[2]);
            acc[3] = fmaf(w, (x.w - mu) * rstd * g4.w + b4.w, acc[3]);
        }
        // ballot-compressed query rectification loop (~Q hits avg)
        int myc = -1; float myw = 0.f, mymu = 0.f, myr = 0.f;
        if (lane < QT) {
            myc  = cq_s[lane]; myw = wq_s[lane];
            mymu = qstat_s[lane][0]; myr = qstat_s[lane][1];
        }
        unsigned long long mask = __ballot(lane < QT && myc == n);
        while (mask) {
            const int q = __ffsll(mask) - 1;
            mask &= mask - 1;
            const float w    = __shfl(myw,  q);
            const float mu   = __shfl(mymu, q);
            const float rstd = __shfl(myr,  q);
            const float4 x = *reinterpret_cast<const float4*>(qryB + (size_t)q * Hh + lane * 4);
            acc[0] = fmaf(w, (x.x - mu) * rstd * g4.x + b4.x, acc[0]);
            acc[1] = fmaf(w, (x.y - mu) * rstd * g4.y + b4.y, acc[1]);
            acc[2] = fmaf(w, (x.z - mu) * rstd * g4.z + b4.z, acc[2]);
            acc[3] = fmaf(w, (x.w - mu) * rstd * g4.w + b4.w, acc[3]);
        }
        const float inv = 1.0f / (float)(Kk + cnt_s[n]);
        float pv[4];
#pragma unroll
        for (int i = 0; i < 4; ++i) pv[i] = acc[i] * inv;
        *reinterpret_cast<float4*>(&proto_s[n][lane * 4]) =
            make_float4(pv[0], pv[1], pv[2], pv[3]);
        float pp = pv[0] * pv[0];
        pp = fmaf(pv[1], pv[1], pp); pp = fmaf(pv[2], pv[2], pp); pp = fmaf(pv[3], pv[3], pp);
        pp = wave64_sum(pp);
        if (lane == 0) np_s[n] = pp;
    }
    __syncthreads();

    // ---------------- F (groups 0-49): logits + pred ----------------
    if (grp < QT) {
        const int q = grp;
        const float* row  = qryB + (size_t)q * Hh;
        const float  mu   = qstat_s[q][0];
        const float  rstd = qstat_s[q][1];
        float y16[16];
#pragma unroll
        for (int c = 0; c < 4; ++c) {
            const int h = c * 64 + sub * 4;
            const float4 x  = *reinterpret_cast<const float4*>(row + h);
            const float4 gg = *reinterpret_cast<const float4*>(g_s + h);
            const float4 bb = *reinterpret_cast<const float4*>(bt_s + h);
            y16[c * 4 + 0] = (x.x - mu) * rstd * gg.x + bb.x;
            y16[c * 4 + 1] = (x.y - mu) * rstd * gg.y + bb.y;
            y16[c * 4 + 2] = (x.z - mu) * rstd * gg.z + bb.z;
            y16[c * 4 + 3] = (x.w - mu) * rstd * gg.w + bb.w;
        }
        const float ny = ny_s[q];

        float mine = 0.f, maxd = -INFINITY, bestd = INFINITY;
        int bestn = 0;
#pragma unroll
        for (int n = 0; n < Nn; ++n) {
            float p = 0.f;
#pragma unroll
            for (int c = 0; c < 4; ++c) {
                const float4 pv = *reinterpret_cast<const float4*>(&proto_s[n][c * 64 + sub * 4]);
                p = fmaf(y16[c * 4 + 0], pv.x, p);
                p = fmaf(y16[c * 4 + 1], pv.y, p);
                p = fmaf(y16[c * 4 + 2], pv.z, p);
                p = fmaf(y16[c * 4 + 3], pv.w, p);
            }
            p = grp16_sum(p);
            const float d = ny + np_s[n] - 2.0f * p;
            if (sub == n) mine = d;
            maxd = fmaxf(maxd, d);
            if (d < bestd) { bestd = d; bestn = n; }
        }
        float* o = out + ((size_t)b * QT + q) * NP1;
        if (sub < Nn)       o[sub] = -mine;
        else if (sub == Nn) o[Nn]  = -maxd - 1.0f;             // min(logits) - 1
        else if (sub == Nn + 1)
            out[(size_t)B * QT * NP1 + (size_t)b * QT + q] = (float)bestn;
    }
}

extern "C" void kernel_launch(void* const* d_in, const int* in_sizes, int n_in,
                              void* d_out, int out_size, void* d_ws, size_t ws_size,
                              hipStream_t stream) {
    const float* support = (const float*)d_in[0];
    const float* query   = (const float*)d_in[1];
    const float* gamma   = (const float*)d_in[2];
    const float* beta    = (const float*)d_in[3];
    float* out = (float*)d_out;

    const int B = in_sizes[0] / (Nn * Kk * Hh);   // 512
    proto_rectify_fused<<<B, 1024, 0, stream>>>(support, query, gamma, beta, out, B);
}

// Round 7
// 29.866 us; speedup vs baseline: 1.7089x; 1.1478x over previous
//
#include <hip/hip_runtime.h>
#include <math.h>

#define LN_EPS 1e-5f

// Problem constants (fixed by setup_inputs): N=10, K=5, Q=5, H=256, Qtot=50
constexpr int Nn  = 10;
constexpr int Kk  = 5;
constexpr int Hh  = 256;
constexpr int QT  = 50;
constexpr int NP1 = 11;

// ---------- DPP-based reductions (VALU pipe; zero DS-pipe ops) ----------
// HIP __shfl_* lower to ds_bpermute (DS pipe). The round-5/6 profile shows
// ~2600 shuffle-DS ops/block serializing on the DS pipe (~12us/CU), so all
// reductions here use DPP adds instead.
template<int CTRL, int RM>
__device__ __forceinline__ float dpp_term(float x) {
    return __int_as_float(__builtin_amdgcn_update_dpp(
        0, __float_as_int(x), CTRL, RM, 0xf, true));   // bound_ctrl: OOB -> 0
}

// broadcast sum across each 16-lane group (4 DPP adds)
__device__ __forceinline__ float sum16_bcast(float v) {
    v += dpp_term<0xB1,  0xf>(v);   // quad_perm [1,0,3,2]  (xor1)
    v += dpp_term<0x4E,  0xf>(v);   // quad_perm [2,3,0,1]  (xor2)
    v += dpp_term<0x124, 0xf>(v);   // row_ror:4  -> mod-4 class sums
    v += dpp_term<0x128, 0xf>(v);   // row_ror:8  -> full 16-sum, all lanes
    return v;
}
// wave sum accumulated into lane 63 (6 DPP adds, AMD-canonical)
__device__ __forceinline__ float sum64_lane63(float v) {
    v += dpp_term<0x111, 0xf>(v);   // row_shr:1
    v += dpp_term<0x112, 0xf>(v);   // row_shr:2
    v += dpp_term<0x114, 0xf>(v);   // row_shr:4
    v += dpp_term<0x118, 0xf>(v);   // row_shr:8   (lane15 of each row = row sum)
    v += dpp_term<0x142, 0xa>(v);   // row_bcast:15 -> rows 1,3 (lane31=r0+r1, lane63=r2+r3)
    v += dpp_term<0x143, 0xc>(v);   // row_bcast:31 -> rows 2,3 (lane63=total)
    return v;
}
__device__ __forceinline__ float rdlane(float v, int l) {
    return __int_as_float(__builtin_amdgcn_readlane(__float_as_int(v), l));
}
__device__ __forceinline__ float wave64_sum_bcast(float v) {
    return rdlane(sum64_lane63(v), 63);
}

// One batch per 1024-thread block (16 waves). 3 barriers total.
// A  (waves 0-9):  LN support inline (stats -> LDS for E), M, ||M||^2, scores.
// A' (waves 10-15): query LN stats (mu,rstd) -> LDS.
// C  (groups 0-49): y16=LN(query), ny->LDS, nearest-M via d=ny+nM-2*dot,
//                   wq/cq/counts.   B (groups 56-60): softmax of scores.
// E  (waves 0-9):  rectified prototype (ballot loop, readlane bcast), ||p||^2.
// F  (groups 0-49): y16 recomputed (L2-hot reload), logits via d=ny+np-2*dot.
// NOTE: nothing register-live across barriers (round-4 spill lesson).
__global__ __launch_bounds__(1024, 8) void proto_rectify_fused(
    const float* __restrict__ support, const float* __restrict__ query,
    const float* __restrict__ gamma,   const float* __restrict__ beta,
    float* __restrict__ out, int B)
{
    const int b    = blockIdx.x;
    const int tid  = threadIdx.x;
    const int lane = tid & 63;
    const int wave = tid >> 6;   // 0..15
    const int grp  = tid >> 4;   // 0..63
    const int sub  = tid & 15;

    __shared__ float g_s[Hh], bt_s[Hh];
    __shared__ float M_s[Nn][Hh];
    __shared__ float proto_s[Nn][Hh];
    __shared__ float nM_s[Nn], np_s[Nn];
    __shared__ float ny_s[QT];
    __shared__ float score_s[Nn * Kk];
    __shared__ float wsup_s[Nn * Kk];
    __shared__ float wq_s[QT];
    __shared__ int   cq_s[QT];
    __shared__ float sstat_s[Nn * Kk][2];  // support row: mu, rstd
    __shared__ float qstat_s[QT][2];       // query row:   mu, rstd
    __shared__ int   cnt_s[Nn];

    const float* supB = support + (size_t)b * (Nn * Kk * Hh);
    const float* qryB = query   + (size_t)b * (QT * Hh);

    // LDS preload runs concurrently with phase A (consumed only after sync 1)
    if (tid < Hh)          g_s[tid]       = gamma[tid];
    else if (tid < 2 * Hh) bt_s[tid - Hh] = beta[tid - Hh];
    if (tid < Nn)          cnt_s[tid]     = 0;

    // ---------------- Phase A / A' ----------------
    if (wave < Nn) {
        const int n = wave;
        const float4 g4 = *reinterpret_cast<const float4*>(gamma + lane * 4); // L1
        const float4 b4 = *reinterpret_cast<const float4*>(beta  + lane * 4);
        const float* rows = supB + (size_t)n * Kk * Hh;

        float y[Kk][4];
#pragma unroll
        for (int k = 0; k < Kk; ++k) {
            const float4 x = *reinterpret_cast<const float4*>(rows + k * Hh + lane * 4);
            float s  = x.x + x.y + x.z + x.w;
            float ss = x.x * x.x + x.y * x.y + x.z * x.z + x.w * x.w;
            s  = wave64_sum_bcast(s);
            ss = wave64_sum_bcast(ss);
            const float mu   = s * (1.0f / (float)Hh);
            const float rstd = rsqrtf(ss * (1.0f / (float)Hh) - mu * mu + LN_EPS);
            if (lane == 0) { sstat_s[n * Kk + k][0] = mu; sstat_s[n * Kk + k][1] = rstd; }
            y[k][0] = (x.x - mu) * rstd * g4.x + b4.x;
            y[k][1] = (x.y - mu) * rstd * g4.y + b4.y;
            y[k][2] = (x.z - mu) * rstd * g4.z + b4.z;
            y[k][3] = (x.w - mu) * rstd * g4.w + b4.w;
        }
        float Mv[4];
#pragma unroll
        for (int i = 0; i < 4; ++i)
            Mv[i] = (y[0][i] + y[1][i] + y[2][i] + y[3][i] + y[4][i]) / 5.0f;
        *reinterpret_cast<float4*>(&M_s[n][lane * 4]) =
            make_float4(Mv[0], Mv[1], Mv[2], Mv[3]);

        float pm = Mv[0] * Mv[0];
        pm = fmaf(Mv[1], Mv[1], pm); pm = fmaf(Mv[2], Mv[2], pm); pm = fmaf(Mv[3], Mv[3], pm);
        pm = sum64_lane63(pm);
        if (lane == 63) nM_s[n] = pm;

#pragma unroll
        for (int k = 0; k < Kk; ++k) {
            float p = y[k][0] * Mv[0];
            p = fmaf(y[k][1], Mv[1], p); p = fmaf(y[k][2], Mv[2], p); p = fmaf(y[k][3], Mv[3], p);
            p = sum64_lane63(p);
            if (lane == 63) score_s[n * Kk + k] = p;
        }
    } else {
        // waves 10..15 -> groups 40..63 (24 groups): query LN stats
        for (int q = grp - 40; q < QT; q += 24) {
            const float* row = qryB + (size_t)q * Hh;
            float s = 0.f, ss = 0.f;
#pragma unroll
            for (int c = 0; c < 4; ++c) {
                const float4 x = *reinterpret_cast<const float4*>(row + c * 64 + sub * 4);
                s  += x.x + x.y + x.z + x.w;
                ss += x.x * x.x + x.y * x.y + x.z * x.z + x.w * x.w;
            }
            s  = sum16_bcast(s);
            ss = sum16_bcast(ss);
            if (sub == 0) {
                const float mu = s * (1.0f / (float)Hh);
                qstat_s[q][0] = mu;
                qstat_s[q][1] = rsqrtf(ss * (1.0f / (float)Hh) - mu * mu + LN_EPS);
            }
        }
    }
    __syncthreads();

    // ---------------- C (groups 0-49) + B (groups 56-60) ----------------
    if (grp < QT) {
        const int q = grp;
        const float* row  = qryB + (size_t)q * Hh;
        const float  mu   = qstat_s[q][0];
        const float  rstd = qstat_s[q][1];
        float y16[16];
#pragma unroll
        for (int c = 0; c < 4; ++c) {
            const int h = c * 64 + sub * 4;
            const float4 x  = *reinterpret_cast<const float4*>(row + h);
            const float4 gg = *reinterpret_cast<const float4*>(g_s + h);
            const float4 bb = *reinterpret_cast<const float4*>(bt_s + h);
            y16[c * 4 + 0] = (x.x - mu) * rstd * gg.x + bb.x;
            y16[c * 4 + 1] = (x.y - mu) * rstd * gg.y + bb.y;
            y16[c * 4 + 2] = (x.z - mu) * rstd * gg.z + bb.z;
            y16[c * 4 + 3] = (x.w - mu) * rstd * gg.w + bb.w;
        }
        float ny = 0.f;
#pragma unroll
        for (int j = 0; j < 16; ++j) ny = fmaf(y16[j], y16[j], ny);
        ny = sum16_bcast(ny);
        if (sub == 0) ny_s[q] = ny;

        float bestd = INFINITY, bestdot = 0.f;
        int bestn = 0;
#pragma unroll
        for (int n = 0; n < Nn; ++n) {
            float p = 0.f;
#pragma unroll
            for (int c = 0; c < 4; ++c) {
                const float4 mv = *reinterpret_cast<const float4*>(&M_s[n][c * 64 + sub * 4]);
                p = fmaf(y16[c * 4 + 0], mv.x, p);
                p = fmaf(y16[c * 4 + 1], mv.y, p);
                p = fmaf(y16[c * 4 + 2], mv.z, p);
                p = fmaf(y16[c * 4 + 3], mv.w, p);
            }
            p = sum16_bcast(p);
            const float d = ny + nM_s[n] - 2.0f * p;
            if (d < bestd) { bestd = d; bestn = n; bestdot = p; }  // first-min tie-break
        }
        if (sub == 0) {
            const float sc  = bestdot;             // <q, M_bestn>
            const float mx  = fmaxf(sc, 0.f);
            const float e   = expf(sc - mx);
            const float den = e + (float)(Nn - 1) * expf(-mx);
            wq_s[q] = e / den;
            cq_s[q] = bestn;
            atomicAdd(&cnt_s[bestn], 1);
        }
    } else if (grp >= 56 && grp < 56 + Kk && sub == 0) {
        const int k = grp - 56;
        float mx = -INFINITY;
#pragma unroll
        for (int n = 0; n < Nn; ++n) mx = fmaxf(mx, score_s[n * Kk + k]);
        float e[Nn]; float den = 0.f;
#pragma unroll
        for (int n = 0; n < Nn; ++n) { e[n] = expf(score_s[n * Kk + k] - mx); den += e[n]; }
#pragma unroll
        for (int n = 0; n < Nn; ++n) wsup_s[n * Kk + k] = e[n] / den;
    }
    __syncthreads();

    // ---------------- E (waves 0-9): rectified prototype ----------------
    if (wave < Nn) {
        const int n = wave;
        const float4 g4 = *reinterpret_cast<const float4*>(g_s  + lane * 4);
        const float4 b4 = *reinterpret_cast<const float4*>(bt_s + lane * 4);
        const float* rows = supB + (size_t)n * Kk * Hh;

        float acc[4] = {0.f, 0.f, 0.f, 0.f};
#pragma unroll
        for (int k = 0; k < Kk; ++k) {
            const float w    = wsup_s[n * Kk + k];
            const float mu   = sstat_s[n * Kk + k][0];
            const float rstd = sstat_s[n * Kk + k][1];
            const float4 x = *reinterpret_cast<const float4*>(rows + k * Hh + lane * 4);
            acc[0] = fmaf(w, (x.x - mu) * rstd * g4.x + b4.x, acc[0]);
            acc[1] = fmaf(w, (x.y - mu) * rstd * g4.y + b4.y, acc[1]);
            acc[2] = fmaf(w, (x.z - mu) * rstd * g4.z + b4.z, acc[2]);
            acc[3] = fmaf(w, (x.w - mu) * rstd * g4.w + b4.w, acc[3]);
        }
        // ballot-compressed query rectification loop; q is wave-uniform so
        // per-q scalars broadcast via readlane (VALU), not shuffles (DS).
        int myc = -1; float myw = 0.f, mymu = 0.f, myr = 0.f;
        if (lane < QT) {
            myc  = cq_s[lane]; myw = wq_s[lane];
            mymu = qstat_s[lane][0]; myr = qstat_s[lane][1];
        }
        unsigned long long mask = __ballot(lane < QT && myc == n);
        while (mask) {
            const int q = __ffsll(mask) - 1;
            mask &= mask - 1;
            const float w    = rdlane(myw,  q);
            const float mu   = rdlane(mymu, q);
            const float rstd = rdlane(myr,  q);
            const float4 x = *reinterpret_cast<const float4*>(qryB + (size_t)q * Hh + lane * 4);
            acc[0] = fmaf(w, (x.x - mu) * rstd * g4.x + b4.x, acc[0]);
            acc[1] = fmaf(w, (x.y - mu) * rstd * g4.y + b4.y, acc[1]);
            acc[2] = fmaf(w, (x.z - mu) * rstd * g4.z + b4.z, acc[2]);
            acc[3] = fmaf(w, (x.w - mu) * rstd * g4.w + b4.w, acc[3]);
        }
        const float inv = 1.0f / (float)(Kk + cnt_s[n]);
        float pv[4];
#pragma unroll
        for (int i = 0; i < 4; ++i) pv[i] = acc[i] * inv;
        *reinterpret_cast<float4*>(&proto_s[n][lane * 4]) =
            make_float4(pv[0], pv[1], pv[2], pv[3]);
        float pp = pv[0] * pv[0];
        pp = fmaf(pv[1], pv[1], pp); pp = fmaf(pv[2], pv[2], pp); pp = fmaf(pv[3], pv[3], pp);
        pp = sum64_lane63(pp);
        if (lane == 63) np_s[n] = pp;
    }
    __syncthreads();

    // ---------------- F (groups 0-49): logits + pred ----------------
    if (grp < QT) {
        const int q = grp;
        const float* row  = qryB + (size_t)q * Hh;
        const float  mu   = qstat_s[q][0];
        const float  rstd = qstat_s[q][1];
        float y16[16];
#pragma unroll
        for (int c = 0; c < 4; ++c) {
            const int h = c * 64 + sub * 4;
            const float4 x  = *reinterpret_cast<const float4*>(row + h);
            const float4 gg = *reinterpret_cast<const float4*>(g_s + h);
            const float4 bb = *reinterpret_cast<const float4*>(bt_s + h);
            y16[c * 4 + 0] = (x.x - mu) * rstd * gg.x + bb.x;
            y16[c * 4 + 1] = (x.y - mu) * rstd * gg.y + bb.y;
            y16[c * 4 + 2] = (x.z - mu) * rstd * gg.z + bb.z;
            y16[c * 4 + 3] = (x.w - mu) * rstd * gg.w + bb.w;
        }
        const float ny = ny_s[q];

        float mine = 0.f, maxd = -INFINITY, bestd = INFINITY;
        int bestn = 0;
#pragma unroll
        for (int n = 0; n < Nn; ++n) {
            float p = 0.f;
#pragma unroll
            for (int c = 0; c < 4; ++c) {
                const float4 pv = *reinterpret_cast<const float4*>(&proto_s[n][c * 64 + sub * 4]);
                p = fmaf(y16[c * 4 + 0], pv.x, p);
                p = fmaf(y16[c * 4 + 1], pv.y, p);
                p = fmaf(y16[c * 4 + 2], pv.z, p);
                p = fmaf(y16[c * 4 + 3], pv.w, p);
            }
            p = sum16_bcast(p);
            const float d = ny + np_s[n] - 2.0f * p;
            if (sub == n) mine = d;
            maxd = fmaxf(maxd, d);
            if (d < bestd) { bestd = d; bestn = n; }
        }
        float* o = out + ((size_t)b * QT + q) * NP1;
        if (sub < Nn)       o[sub] = -mine;
        else if (sub == Nn) o[Nn]  = -maxd - 1.0f;             // min(logits) - 1
        else if (sub == Nn + 1)
            out[(size_t)B * QT * NP1 + (size_t)b * QT + q] = (float)bestn;
    }
}

extern "C" void kernel_launch(void* const* d_in, const int* in_sizes, int n_in,
                              void* d_out, int out_size, void* d_ws, size_t ws_size,
                              hipStream_t stream) {
    const float* support = (const float*)d_in[0];
    const float* query   = (const float*)d_in[1];
    const float* gamma   = (const float*)d_in[2];
    const float* beta    = (const float*)d_in[3];
    float* out = (float*)d_out;

    const int B = in_sizes[0] / (Nn * Kk * Hh);   // 512
    proto_rectify_fused<<<B, 1024, 0, stream>>>(support, query, gamma, beta, out, B);
}

// Round 8
// 28.637 us; speedup vs baseline: 1.7822x; 1.0429x over previous
//
#include <hip/hip_runtime.h>
#include <math.h>

#define LN_EPS 1e-5f

// Problem constants (fixed by setup_inputs): N=10, K=5, Q=5, H=256, Qtot=50
constexpr int Nn  = 10;
constexpr int Kk  = 5;
constexpr int Hh  = 256;
constexpr int QT  = 50;
constexpr int NP1 = 11;

// ---------- DPP-based reductions (VALU pipe; zero DS-pipe ops) ----------
template<int CTRL, int RM>
__device__ __forceinline__ float dpp_term(float x) {
    return __int_as_float(__builtin_amdgcn_update_dpp(
        0, __float_as_int(x), CTRL, RM, 0xf, true));   // bound_ctrl: OOB -> 0
}

// broadcast sum across each 16-lane group (4 DPP adds)
__device__ __forceinline__ float sum16_bcast(float v) {
    v += dpp_term<0xB1,  0xf>(v);   // quad_perm [1,0,3,2]
    v += dpp_term<0x4E,  0xf>(v);   // quad_perm [2,3,0,1]
    v += dpp_term<0x124, 0xf>(v);   // row_ror:4
    v += dpp_term<0x128, 0xf>(v);   // row_ror:8 -> full 16-sum, all lanes
    return v;
}
// wave sum accumulated into lane 63 (6 DPP adds)
__device__ __forceinline__ float sum64_lane63(float v) {
    v += dpp_term<0x111, 0xf>(v);   // row_shr:1
    v += dpp_term<0x112, 0xf>(v);   // row_shr:2
    v += dpp_term<0x114, 0xf>(v);   // row_shr:4
    v += dpp_term<0x118, 0xf>(v);   // row_shr:8
    v += dpp_term<0x142, 0xa>(v);   // row_bcast:15 -> rows 1,3
    v += dpp_term<0x143, 0xc>(v);   // row_bcast:31 -> rows 2,3 (lane63 = total)
    return v;
}
__device__ __forceinline__ float rdlane(float v, int l) {
    return __int_as_float(__builtin_amdgcn_readlane(__float_as_int(v), l));
}
__device__ __forceinline__ float wave64_sum_bcast(float v) {
    return rdlane(sum64_lane63(v), 63);
}

// One batch per 1024-thread block (16 waves). 3 barriers.
// A  (waves 0-9):  support-only streaming: LN inline (stats->LDS for E),
//                  M, ||M||^2, scores. Waves 10-15 only preload gamma/beta.
// C  (groups 0-49): query row loaded ONCE: fused LN stats (sum16) -> qstat,
//                  y16 in-place, ny->LDS, argmin over (nM-2*dot) [== argmin
//                  of distance, ny is a per-q constant], wq/cq/counts.
//                  Query HBM streaming overlaps C's compute (phase A' removed).
//   B (groups 56-60): per-k softmax over N of support scores.
// E  (waves 0-9):  rectified prototype (ballot loop, readlane bcast), ||p||^2.
// F  (groups 0-49): y16 recomputed from qstat (L2-hot reload), logits via
//                  d = ny + np - 2*dot, pred.
// NOTE: nothing register-live across barriers (round-4 spill lesson).
__global__ __launch_bounds__(1024, 8) void proto_rectify_fused(
    const float* __restrict__ support, const float* __restrict__ query,
    const float* __restrict__ gamma,   const float* __restrict__ beta,
    float* __restrict__ out, int B)
{
    const int b    = blockIdx.x;
    const int tid  = threadIdx.x;
    const int lane = tid & 63;
    const int wave = tid >> 6;   // 0..15
    const int grp  = tid >> 4;   // 0..63
    const int sub  = tid & 15;

    __shared__ float g_s[Hh], bt_s[Hh];
    __shared__ float M_s[Nn][Hh];
    __shared__ float proto_s[Nn][Hh];
    __shared__ float nM_s[Nn], np_s[Nn];
    __shared__ float ny_s[QT];
    __shared__ float score_s[Nn * Kk];
    __shared__ float wsup_s[Nn * Kk];
    __shared__ float wq_s[QT];
    __shared__ int   cq_s[QT];
    __shared__ float sstat_s[Nn * Kk][2];  // support row: mu, rstd
    __shared__ float qstat_s[QT][2];       // query row:   mu, rstd
    __shared__ int   cnt_s[Nn];

    const float* supB = support + (size_t)b * (Nn * Kk * Hh);
    const float* qryB = query   + (size_t)b * (QT * Hh);

    // LDS preload runs concurrently with phase A (consumed only after sync 1)
    if (tid < Hh)          g_s[tid]       = gamma[tid];
    else if (tid < 2 * Hh) bt_s[tid - Hh] = beta[tid - Hh];
    if (tid < Nn)          cnt_s[tid]     = 0;

    // ---------------- Phase A: support only (waves 0-9) ----------------
    if (wave < Nn) {
        const int n = wave;
        const float4 g4 = *reinterpret_cast<const float4*>(gamma + lane * 4); // L1
        const float4 b4 = *reinterpret_cast<const float4*>(beta  + lane * 4);
        const float* rows = supB + (size_t)n * Kk * Hh;

        float y[Kk][4];
#pragma unroll
        for (int k = 0; k < Kk; ++k) {
            const float4 x = *reinterpret_cast<const float4*>(rows + k * Hh + lane * 4);
            float s  = x.x + x.y + x.z + x.w;
            float ss = x.x * x.x + x.y * x.y + x.z * x.z + x.w * x.w;
            s  = wave64_sum_bcast(s);
            ss = wave64_sum_bcast(ss);
            const float mu   = s * (1.0f / (float)Hh);
            const float rstd = rsqrtf(ss * (1.0f / (float)Hh) - mu * mu + LN_EPS);
            if (lane == 0) { sstat_s[n * Kk + k][0] = mu; sstat_s[n * Kk + k][1] = rstd; }
            y[k][0] = (x.x - mu) * rstd * g4.x + b4.x;
            y[k][1] = (x.y - mu) * rstd * g4.y + b4.y;
            y[k][2] = (x.z - mu) * rstd * g4.z + b4.z;
            y[k][3] = (x.w - mu) * rstd * g4.w + b4.w;
        }
        float Mv[4];
#pragma unroll
        for (int i = 0; i < 4; ++i)
            Mv[i] = (y[0][i] + y[1][i] + y[2][i] + y[3][i] + y[4][i]) / 5.0f;
        *reinterpret_cast<float4*>(&M_s[n][lane * 4]) =
            make_float4(Mv[0], Mv[1], Mv[2], Mv[3]);

        float pm = Mv[0] * Mv[0];
        pm = fmaf(Mv[1], Mv[1], pm); pm = fmaf(Mv[2], Mv[2], pm); pm = fmaf(Mv[3], Mv[3], pm);
        pm = sum64_lane63(pm);
        if (lane == 63) nM_s[n] = pm;

#pragma unroll
        for (int k = 0; k < Kk; ++k) {
            float p = y[k][0] * Mv[0];
            p = fmaf(y[k][1], Mv[1], p); p = fmaf(y[k][2], Mv[2], p); p = fmaf(y[k][3], Mv[3], p);
            p = sum64_lane63(p);
            if (lane == 63) score_s[n * Kk + k] = p;
        }
    }
    __syncthreads();

    // ---------------- C (groups 0-49, fused LN stats) + B (groups 56-60) -----
    if (grp < QT) {
        const int q = grp;
        const float* row = qryB + (size_t)q * Hh;
        float y16[16];
        float s = 0.f, ss = 0.f;
#pragma unroll
        for (int c = 0; c < 4; ++c) {
            const float4 x = *reinterpret_cast<const float4*>(row + c * 64 + sub * 4);
            y16[c * 4 + 0] = x.x; y16[c * 4 + 1] = x.y;
            y16[c * 4 + 2] = x.z; y16[c * 4 + 3] = x.w;
            s  += x.x + x.y + x.z + x.w;
            ss  = fmaf(x.x, x.x, ss); ss = fmaf(x.y, x.y, ss);
            ss  = fmaf(x.z, x.z, ss); ss = fmaf(x.w, x.w, ss);
        }
        s  = sum16_bcast(s);
        ss = sum16_bcast(ss);
        const float mu   = s * (1.0f / (float)Hh);
        const float rstd = rsqrtf(ss * (1.0f / (float)Hh) - mu * mu + LN_EPS);
        if (sub == 0) { qstat_s[q][0] = mu; qstat_s[q][1] = rstd; }

#pragma unroll
        for (int c = 0; c < 4; ++c) {
            const int h = c * 64 + sub * 4;
            const float4 gg = *reinterpret_cast<const float4*>(g_s + h);
            const float4 bb = *reinterpret_cast<const float4*>(bt_s + h);
            y16[c * 4 + 0] = (y16[c * 4 + 0] - mu) * rstd * gg.x + bb.x;
            y16[c * 4 + 1] = (y16[c * 4 + 1] - mu) * rstd * gg.y + bb.y;
            y16[c * 4 + 2] = (y16[c * 4 + 2] - mu) * rstd * gg.z + bb.z;
            y16[c * 4 + 3] = (y16[c * 4 + 3] - mu) * rstd * gg.w + bb.w;
        }
        float ny = 0.f;
#pragma unroll
        for (int j = 0; j < 16; ++j) ny = fmaf(y16[j], y16[j], ny);
        ny = sum16_bcast(ny);
        if (sub == 0) ny_s[q] = ny;

        // argmin_n (ny + nM - 2p) == argmin_n (nM - 2p): ny is constant per q
        float bestd = INFINITY, bestdot = 0.f;
        int bestn = 0;
#pragma unroll
        for (int n = 0; n < Nn; ++n) {
            float p = 0.f;
#pragma unroll
            for (int c = 0; c < 4; ++c) {
                const float4 mv = *reinterpret_cast<const float4*>(&M_s[n][c * 64 + sub * 4]);
                p = fmaf(y16[c * 4 + 0], mv.x, p);
                p = fmaf(y16[c * 4 + 1], mv.y, p);
                p = fmaf(y16[c * 4 + 2], mv.z, p);
                p = fmaf(y16[c * 4 + 3], mv.w, p);
            }
            p = sum16_bcast(p);
            const float d = nM_s[n] - 2.0f * p;
            if (d < bestd) { bestd = d; bestn = n; bestdot = p; }  // first-min tie-break
        }
        if (sub == 0) {
            const float sc  = bestdot;             // <q, M_bestn>
            const float mx  = fmaxf(sc, 0.f);
            const float e   = expf(sc - mx);
            const float den = e + (float)(Nn - 1) * expf(-mx);
            wq_s[q] = e / den;
            cq_s[q] = bestn;
            atomicAdd(&cnt_s[bestn], 1);
        }
    } else if (grp >= 56 && grp < 56 + Kk && sub == 0) {
        const int k = grp - 56;
        float mx = -INFINITY;
#pragma unroll
        for (int n = 0; n < Nn; ++n) mx = fmaxf(mx, score_s[n * Kk + k]);
        float e[Nn]; float den = 0.f;
#pragma unroll
        for (int n = 0; n < Nn; ++n) { e[n] = expf(score_s[n * Kk + k] - mx); den += e[n]; }
#pragma unroll
        for (int n = 0; n < Nn; ++n) wsup_s[n * Kk + k] = e[n] / den;
    }
    __syncthreads();

    // ---------------- E (waves 0-9): rectified prototype ----------------
    if (wave < Nn) {
        const int n = wave;
        const float4 g4 = *reinterpret_cast<const float4*>(g_s  + lane * 4);
        const float4 b4 = *reinterpret_cast<const float4*>(bt_s + lane * 4);
        const float* rows = supB + (size_t)n * Kk * Hh;

        float acc[4] = {0.f, 0.f, 0.f, 0.f};
#pragma unroll
        for (int k = 0; k < Kk; ++k) {
            const float w    = wsup_s[n * Kk + k];
            const float mu   = sstat_s[n * Kk + k][0];
            const float rstd = sstat_s[n * Kk + k][1];
            const float4 x = *reinterpret_cast<const float4*>(rows + k * Hh + lane * 4);
            acc[0] = fmaf(w, (x.x - mu) * rstd * g4.x + b4.x, acc[0]);
            acc[1] = fmaf(w, (x.y - mu) * rstd * g4.y + b4.y, acc[1]);
            acc[2] = fmaf(w, (x.z - mu) * rstd * g4.z + b4.z, acc[2]);
            acc[3] = fmaf(w, (x.w - mu) * rstd * g4.w + b4.w, acc[3]);
        }
        // ballot-compressed query rectification; per-q scalars via readlane (VALU)
        int myc = -1; float myw = 0.f, mymu = 0.f, myr = 0.f;
        if (lane < QT) {
            myc  = cq_s[lane]; myw = wq_s[lane];
            mymu = qstat_s[lane][0]; myr = qstat_s[lane][1];
        }
        unsigned long long mask = __ballot(lane < QT && myc == n);
        while (mask) {
            const int q = __ffsll(mask) - 1;
            mask &= mask - 1;
            const float w    = rdlane(myw,  q);
            const float mu   = rdlane(mymu, q);
            const float rstd = rdlane(myr,  q);
            const float4 x = *reinterpret_cast<const float4*>(qryB + (size_t)q * Hh + lane * 4);
            acc[0] = fmaf(w, (x.x - mu) * rstd * g4.x + b4.x, acc[0]);
            acc[1] = fmaf(w, (x.y - mu) * rstd * g4.y + b4.y, acc[1]);
            acc[2] = fmaf(w, (x.z - mu) * rstd * g4.z + b4.z, acc[2]);
            acc[3] = fmaf(w, (x.w - mu) * rstd * g4.w + b4.w, acc[3]);
        }
        const float inv = 1.0f / (float)(Kk + cnt_s[n]);
        float pv[4];
#pragma unroll
        for (int i = 0; i < 4; ++i) pv[i] = acc[i] * inv;
        *reinterpret_cast<float4*>(&proto_s[n][lane * 4]) =
            make_float4(pv[0], pv[1], pv[2], pv[3]);
        float pp = pv[0] * pv[0];
        pp = fmaf(pv[1], pv[1], pp); pp = fmaf(pv[2], pv[2], pp); pp = fmaf(pv[3], pv[3], pp);
        pp = sum64_lane63(pp);
        if (lane == 63) np_s[n] = pp;
    }
    __syncthreads();

    // ---------------- F (groups 0-49): logits + pred ----------------
    if (grp < QT) {
        const int q = grp;
        const float* row  = qryB + (size_t)q * Hh;
        const float  mu   = qstat_s[q][0];
        const float  rstd = qstat_s[q][1];
        float y16[16];
#pragma unroll
        for (int c = 0; c < 4; ++c) {
            const int h = c * 64 + sub * 4;
            const float4 x  = *reinterpret_cast<const float4*>(row + h);
            const float4 gg = *reinterpret_cast<const float4*>(g_s + h);
            const float4 bb = *reinterpret_cast<const float4*>(bt_s + h);
            y16[c * 4 + 0] = (x.x - mu) * rstd * gg.x + bb.x;
            y16[c * 4 + 1] = (x.y - mu) * rstd * gg.y + bb.y;
            y16[c * 4 + 2] = (x.z - mu) * rstd * gg.z + bb.z;
            y16[c * 4 + 3] = (x.w - mu) * rstd * gg.w + bb.w;
        }
        const float ny = ny_s[q];

        float mine = 0.f, maxd = -INFINITY, bestd = INFINITY;
        int bestn = 0;
#pragma unroll
        for (int n = 0; n < Nn; ++n) {
            float p = 0.f;
#pragma unroll
            for (int c = 0; c < 4; ++c) {
                const float4 pv = *reinterpret_cast<const float4*>(&proto_s[n][c * 64 + sub * 4]);
                p = fmaf(y16[c * 4 + 0], pv.x, p);
                p = fmaf(y16[c * 4 + 1], pv.y, p);
                p = fmaf(y16[c * 4 + 2], pv.z, p);
                p = fmaf(y16[c * 4 + 3], pv.w, p);
            }
            p = sum16_bcast(p);
            const float d = ny + np_s[n] - 2.0f * p;
            if (sub == n) mine = d;
            maxd = fmaxf(maxd, d);
            if (d < bestd) { bestd = d; bestn = n; }
        }
        float* o = out + ((size_t)b * QT + q) * NP1;
        if (sub < Nn)       o[sub] = -mine;
        else if (sub == Nn) o[Nn]  = -maxd - 1.0f;             // min(logits) - 1
        else if (sub == Nn + 1)
            out[(size_t)B * QT * NP1 + (size_t)b * QT + q] = (float)bestn;
    }
}

extern "C" void kernel_launch(void* const* d_in, const int* in_sizes, int n_in,
                              void* d_out, int out_size, void* d_ws, size_t ws_size,
                              hipStream_t stream) {
    const float* support = (const float*)d_in[0];
    const float* query   = (const float*)d_in[1];
    const float* gamma   = (const float*)d_in[2];
    const float* beta    = (const float*)d_in[3];
    float* out = (float*)d_out;

    const int B = in_sizes[0] / (Nn * Kk * Hh);   // 512
    proto_rectify_fused<<<B, 1024, 0, stream>>>(support, query, gamma, beta, out, B);
}